// Round 11
// baseline (26.940 us; speedup 1.0000x reference)
//
#include <hip/hip_runtime.h>

// Lovasz-Softmax without sorting (exact up to bin-midpoint error <= 0.5/NB):
//  - ties in the error don't change the loss (telescoping within equal-error
//    groups); jaccard is monotone with total variation 1 -> binning to NB bins
//    with midpoints has per-class error <= 0.5/NB (3.9e-3 at NB=128 vs 1.67e-2
//    threshold; measured 0.0 at NB=128/256).
// R11 = R10 (24.85us) + scanfinal merged into hist via FENCE-FREE ticket:
//  - R9's failure was __threadfence (L2 wb/inv x512 blocks -> 175us), NOT the
//    merge. Ordering here is free: flush atomicAdds are device-scope RMWs
//    performed at the coherence point; __syncthreads emits s_waitcnt vmcnt(0)
//    per wave (m97 asm) so after the barrier all block RMWs are performed;
//    ticket is a RELAXED RMW (no wb/inv emitted); winner reads ghist with
//    relaxed agent loads (bypass local caches). 2 dispatches total.

constexpr int NCLS = 6;
constexpr int HW   = 512 * 512;
constexpr int NPIX = 8 * HW;
constexpr int NB   = 128;        // bin width 1/128 -> loss error <= 3.9e-3
constexpr int NROWS = 2 * NCLS;  // rows 0..5: non-fg (p_c); 6..11: fg (1-p_lab)
constexpr int HIST_WORDS = NROWS * NB;     // 1536
constexpr int NSUB = 8;
constexpr int SUBSTRIDE = HIST_WORDS + 8;  // 1544; %32==8 -> bank-shifted copies
constexpr int NREG = 8;                    // global flush regions
constexpr int GHIST_WORDS = NREG * HIST_WORDS;  // 12288 (+1 ticket word)

constexpr int HBLK = 512;        // 1 quad per thread exactly
constexpr int HTHR = 1024;

__global__ __launch_bounds__(1024) void lovasz_zero(unsigned* __restrict__ g) {
  int i = blockIdx.x * 1024 + threadIdx.x;
  if (i < GHIST_WORDS + 1) g[i] = 0u;      // +1: ticket counter
}

__global__ __launch_bounds__(HTHR) void lovasz_hist(
    const float* __restrict__ logits, const int* __restrict__ labels,
    unsigned* __restrict__ ghist, float* __restrict__ out) {
  __shared__ unsigned lh[NSUB * SUBSTRIDE];  // ~48.3 KB
  __shared__ unsigned s_ticket;
  __shared__ double   sloss[NCLS];
  __shared__ unsigned spres[NCLS];

  for (int i = threadIdx.x; i < NSUB * SUBSTRIDE; i += HTHR) lh[i] = 0u;
  __syncthreads();

  const int sub = (threadIdx.x & 7) * SUBSTRIDE;    // 8 lanes per copy
  const int q  = blockIdx.x * HTHR + threadIdx.x;   // 0 .. 524287
  const int n4 = q << 2;
  const int b  = n4 >> 18;                   // / HW
  const int hw = n4 & (HW - 1);

  int4 lab4 = *reinterpret_cast<const int4*>(labels + n4);
  int labs[4] = {lab4.x, lab4.y, lab4.z, lab4.w};
  if ((lab4.x | lab4.y | lab4.z | lab4.w) != 0) {   // else all ignored: skip
    float xx[NCLS][4];
    size_t base = ((size_t)b * NCLS) << 18;
#pragma unroll
    for (int c = 0; c < NCLS; ++c) {
      float4 v = *reinterpret_cast<const float4*>(logits + base + ((size_t)c << 18) + hw);
      xx[c][0] = v.x; xx[c][1] = v.y; xx[c][2] = v.z; xx[c][3] = v.w;
    }

#pragma unroll
    for (int j = 0; j < 4; ++j) {
      int lab = labs[j];
      if (lab == 0) continue;                // IGNORE: contributes exactly 0
      float m = xx[0][j];
#pragma unroll
      for (int c = 1; c < NCLS; ++c) m = fmaxf(m, xx[c][j]);
      float e[NCLS];
      float s = 0.f;
#pragma unroll
      for (int c = 0; c < NCLS; ++c) { e[c] = __expf(xx[c][j] - m); s += e[c]; }
      float inv = 1.0f / s;
#pragma unroll
      for (int c = 0; c < NCLS; ++c) {
        float p   = e[c] * inv;
        bool  fg  = (c == lab);
        float err = fg ? 1.0f - p : p;
        int bin = (int)(err * (float)NB);
        bin = bin < 0 ? 0 : (bin > NB - 1 ? NB - 1 : bin);
        int row = fg ? NCLS + c : c;
        atomicAdd(&lh[sub + row * NB + bin], 1u);
      }
    }
  }

  __syncthreads();
  unsigned* gbase = ghist + (blockIdx.x & (NREG - 1)) * HIST_WORDS;
  for (int i = threadIdx.x; i < HIST_WORDS; i += HTHR) {
    unsigned v = 0;
#pragma unroll
    for (int k = 0; k < NSUB; ++k) v += lh[k * SUBSTRIDE + i];
    if (v) atomicAdd(&gbase[i], v);
  }

  // ---- fence-free last-block ticket ----
  // __syncthreads implies s_waitcnt vmcnt(0) per wave -> this block's flush
  // RMWs are performed at the coherence point before the ticket RMW issues.
  __syncthreads();
  if (threadIdx.x == 0)
    s_ticket = __hip_atomic_fetch_add(ghist + GHIST_WORDS, 1u,
                                      __ATOMIC_RELAXED, __HIP_MEMORY_SCOPE_AGENT);
  __syncthreads();
  if (s_ticket != HBLK - 1) return;

  // ---- winner block: 6-wave scan (wave w = class w) + final average ----
  const int t = threadIdx.x;
  if (t < 64 * NCLS) {
    const int wave = t >> 6;               // class index
    const int lane = t & 63;
    constexpr int K = NB / 64;             // 2 bins per lane
    const int base = NB - K - lane * K;    // lane 0 -> highest bins

    unsigned a[K], f[K];
#pragma unroll
    for (int i = 0; i < K; ++i) {
      unsigned sa = 0, sf2 = 0;
#pragma unroll
      for (int r = 0; r < NREG; ++r) {
        sa  += __hip_atomic_load(&ghist[r * HIST_WORDS + wave * NB + base + i],
                                 __ATOMIC_RELAXED, __HIP_MEMORY_SCOPE_AGENT);
        sf2 += __hip_atomic_load(&ghist[r * HIST_WORDS + (NCLS + wave) * NB + base + i],
                                 __ATOMIC_RELAXED, __HIP_MEMORY_SCOPE_AGENT);
      }
      a[i] = sa; f[i] = sf2;
    }

    unsigned dn = 0, df = 0;
#pragma unroll
    for (int i = 0; i < K; ++i) { dn += a[i] + f[i]; df += f[i]; }

    unsigned sn = dn, sf = df;             // inclusive wave scan
    for (int off = 1; off < 64; off <<= 1) {
      unsigned tn = __shfl_up(sn, off);
      unsigned tf = __shfl_up(sf, off);
      if (lane >= off) { sn += tn; sf += tf; }
    }
    const unsigned total_f = __shfl(sf, 63); // gts
    unsigned n  = sn - dn;                 // exclusive prefix (larger errors)
    unsigned ff = sf - df;

    double contrib = 0.0;
    if (total_f > 0) {
      const double gts = (double)total_f;
      for (int i = K - 1; i >= 0; --i) {   // descending bins within chunk
        unsigned dnb = a[i] + f[i];
        if (!dnb) continue;
        unsigned dfb = f[i];
        double ub = gts + (double)n - (double)ff;
        double jb = 1.0 - (gts - (double)ff) / ub;
        n += dnb; ff += dfb;
        double ua = gts + (double)n - (double)ff;
        double ja = 1.0 - (gts - (double)ff) / ua;
        contrib += ((double)(base + i) + 0.5) * (1.0 / (double)NB) * (ja - jb);
      }
    }
    for (int off = 32; off > 0; off >>= 1) contrib += __shfl_down(contrib, off);
    if (lane == 0) { sloss[wave] = contrib; spres[wave] = total_f; }
  }
  __syncthreads();
  if (t == 0) {
    double s = 0.0, np = 0.0;
    for (int k = 0; k < NCLS; ++k)
      if (spres[k]) { s += sloss[k]; np += 1.0; }
    out[0] = (float)(s / (np > 0.0 ? np : 1.0));
  }
}

extern "C" void kernel_launch(void* const* d_in, const int* in_sizes, int n_in,
                              void* d_out, int out_size, void* d_ws, size_t ws_size,
                              hipStream_t stream) {
  const float* logits = (const float*)d_in[0];
  const int*   labels = (const int*)d_in[1];
  unsigned*    ghist  = (unsigned*)d_ws;

  lovasz_zero<<<(GHIST_WORDS + 1 + 1023) / 1024, 1024, 0, stream>>>(ghist);
  lovasz_hist<<<HBLK, HTHR, 0, stream>>>(logits, labels, ghist, (float*)d_out);
}

// Round 12
// 23.847 us; speedup vs baseline: 1.1297x; 1.1297x over previous
//
#include <hip/hip_runtime.h>

// Lovasz-Softmax without sorting (exact up to bin-midpoint error <= 0.5/NB):
//  - ties in the error don't change the loss (telescoping within equal-error
//    groups); jaccard is monotone with total variation 1 -> binning to NB bins
//    with midpoints has per-class error <= 0.5/NB (7.8e-3 at NB=64 vs 1.67e-2
//    threshold; measured absmax 0.0 at NB=128/256 - midpoint errors cancel).
// R12 = R10 structure (best, 24.85us; all dispatch-count restructurings -
// coop grid R4, spin flags R5, fenced ticket R9, fence-free ticket R11 -
// regressed or tied) with NSUB 8->16, NB 128->64:
//  - only 4 lanes share a sub-histogram copy -> another ~2x cut in
//    same-address LDS atomic serialization (trend: R7 -3.4us @4 copies,
//    R10 -1.5us @8 copies).

constexpr int NCLS = 6;
constexpr int HW   = 512 * 512;
constexpr int NPIX = 8 * HW;
constexpr int NB   = 64;         // bin width 1/64 -> loss error <= 7.8e-3
constexpr int NROWS = 2 * NCLS;  // rows 0..5: non-fg (p_c); 6..11: fg (1-p_lab)
constexpr int HIST_WORDS = NROWS * NB;     // 768
constexpr int NSUB = 16;
constexpr int SUBSTRIDE = HIST_WORDS + 8;  // 776; %32==8 -> bank-shifted copies
constexpr int NREG = 8;                    // global flush regions
constexpr int GHIST_WORDS = NREG * HIST_WORDS;  // 6144

constexpr int HBLK = 512;        // 1 quad per thread exactly
constexpr int HTHR = 1024;

__global__ __launch_bounds__(1024) void lovasz_zero(unsigned* __restrict__ g) {
  int i = blockIdx.x * 1024 + threadIdx.x;
  if (i < GHIST_WORDS) g[i] = 0u;
}

__global__ __launch_bounds__(HTHR) void lovasz_hist(
    const float* __restrict__ logits, const int* __restrict__ labels,
    unsigned* __restrict__ ghist) {
  __shared__ unsigned lh[NSUB * SUBSTRIDE];  // ~48.5 KB
  for (int i = threadIdx.x; i < NSUB * SUBSTRIDE; i += HTHR) lh[i] = 0u;
  __syncthreads();

  const int sub = (threadIdx.x & 15) * SUBSTRIDE;   // 4 lanes per copy
  const int q  = blockIdx.x * HTHR + threadIdx.x;   // 0 .. 524287
  const int n4 = q << 2;
  const int b  = n4 >> 18;                   // / HW
  const int hw = n4 & (HW - 1);

  int4 lab4 = *reinterpret_cast<const int4*>(labels + n4);
  int labs[4] = {lab4.x, lab4.y, lab4.z, lab4.w};
  if ((lab4.x | lab4.y | lab4.z | lab4.w) != 0) {   // else all ignored: skip
    float xx[NCLS][4];
    size_t base = ((size_t)b * NCLS) << 18;
#pragma unroll
    for (int c = 0; c < NCLS; ++c) {
      float4 v = *reinterpret_cast<const float4*>(logits + base + ((size_t)c << 18) + hw);
      xx[c][0] = v.x; xx[c][1] = v.y; xx[c][2] = v.z; xx[c][3] = v.w;
    }

#pragma unroll
    for (int j = 0; j < 4; ++j) {
      int lab = labs[j];
      if (lab == 0) continue;                // IGNORE: contributes exactly 0
      float m = xx[0][j];
#pragma unroll
      for (int c = 1; c < NCLS; ++c) m = fmaxf(m, xx[c][j]);
      float e[NCLS];
      float s = 0.f;
#pragma unroll
      for (int c = 0; c < NCLS; ++c) { e[c] = __expf(xx[c][j] - m); s += e[c]; }
      float inv = 1.0f / s;
#pragma unroll
      for (int c = 0; c < NCLS; ++c) {
        float p   = e[c] * inv;
        bool  fg  = (c == lab);
        float err = fg ? 1.0f - p : p;
        int bin = (int)(err * (float)NB);
        bin = bin < 0 ? 0 : (bin > NB - 1 ? NB - 1 : bin);
        int row = fg ? NCLS + c : c;
        atomicAdd(&lh[sub + row * NB + bin], 1u);
      }
    }
  }

  __syncthreads();
  unsigned* gbase = ghist + (blockIdx.x & (NREG - 1)) * HIST_WORDS;
  for (int i = threadIdx.x; i < HIST_WORDS; i += HTHR) {
    unsigned v = 0;
#pragma unroll
    for (int k = 0; k < NSUB; ++k) v += lh[k * SUBSTRIDE + i];
    if (v) atomicAdd(&gbase[i], v);
  }
}

// One block, 6 waves: wave w handles class w. Each lane owns 1 bin;
// lane 0 has the highest-error bin so lane order == descending order.
__global__ __launch_bounds__(64 * NCLS) void lovasz_scanfinal(
    const unsigned* __restrict__ ghist, float* __restrict__ out) {
  const int wave = threadIdx.x >> 6;       // class index
  const int lane = threadIdx.x & 63;
  const int bidx = NB - 1 - lane;          // lane 0 -> highest bin

  unsigned a = 0, f = 0;
#pragma unroll
  for (int r = 0; r < NREG; ++r) {
    a += ghist[r * HIST_WORDS + wave * NB + bidx];
    f += ghist[r * HIST_WORDS + (NCLS + wave) * NB + bidx];
  }

  unsigned dn = a + f, df = f;
  unsigned sn = dn, sf = df;               // inclusive wave scan
  for (int off = 1; off < 64; off <<= 1) {
    unsigned tn = __shfl_up(sn, off);
    unsigned tf = __shfl_up(sf, off);
    if (lane >= off) { sn += tn; sf += tf; }
  }
  const unsigned total_f = __shfl(sf, 63); // gts
  const unsigned n0 = sn - dn;             // exclusive prefix (larger errors)
  const unsigned f0 = sf - df;

  double contrib = 0.0;
  if (total_f > 0 && dn) {
    const double gts = (double)total_f;
    double ub = gts + (double)n0 - (double)f0;
    double jb = 1.0 - (gts - (double)f0) / ub;
    double ua = gts + (double)sn - (double)sf;
    double ja = 1.0 - (gts - (double)sf) / ua;
    contrib = ((double)bidx + 0.5) * (1.0 / (double)NB) * (ja - jb);
  }
  for (int off = 32; off > 0; off >>= 1) contrib += __shfl_down(contrib, off);

  __shared__ double   sloss[NCLS];
  __shared__ unsigned spres[NCLS];
  if (lane == 0) { sloss[wave] = contrib; spres[wave] = total_f; }
  __syncthreads();
  if (threadIdx.x == 0) {
    double s = 0.0, np = 0.0;
    for (int k = 0; k < NCLS; ++k)
      if (spres[k]) { s += sloss[k]; np += 1.0; }
    out[0] = (float)(s / (np > 0.0 ? np : 1.0));
  }
}

extern "C" void kernel_launch(void* const* d_in, const int* in_sizes, int n_in,
                              void* d_out, int out_size, void* d_ws, size_t ws_size,
                              hipStream_t stream) {
  const float* logits = (const float*)d_in[0];
  const int*   labels = (const int*)d_in[1];
  unsigned*    ghist  = (unsigned*)d_ws;

  lovasz_zero<<<(GHIST_WORDS + 1023) / 1024, 1024, 0, stream>>>(ghist);
  lovasz_hist<<<HBLK, HTHR, 0, stream>>>(logits, labels, ghist);
  lovasz_scanfinal<<<1, 64 * NCLS, 0, stream>>>(ghist, (float*)d_out);
}